// Round 7
// baseline (5629.494 us; speedup 1.0000x reference)
//
#include <hip/hip_runtime.h>
#include <hip/hip_bf16.h>
#include <stdint.h>

#define Bn 64
#define Tn 512
#define Hn 1024
#define Ln 4
#define GN 4096   // 4*H
#define NDIAG (Tn + Ln - 1)
#define LBH (Ln * Bn * Hn)

typedef __attribute__((ext_vector_type(8))) short bf16x8;
typedef __attribute__((ext_vector_type(4))) float f32x4;
typedef __attribute__((ext_vector_type(4))) unsigned short u16x4;

__device__ __forceinline__ unsigned short f2bf(float f) {
  union { float f; unsigned u; } v; v.f = f;
  return (unsigned short)((v.u + 0x7FFFu + ((v.u >> 16) & 1u)) >> 16);
}

// cached (normal) global->LDS 16B
__device__ __forceinline__ void gload16(const void* g, void* l) {
  __builtin_amdgcn_global_load_lds((const __attribute__((address_space(1))) void*)g,
                                   (__attribute__((address_space(3))) void*)l, 16, 0, 0);
}
// device-coherent global->LDS 16B: aux = sc0|sc1 -> bypass L1/L2, read LLC
__device__ __forceinline__ void gload16c(const void* g, void* l) {
  __builtin_amdgcn_global_load_lds((const __attribute__((address_space(1))) void*)g,
                                   (__attribute__((address_space(3))) void*)l, 16, 0, 17);
}

__device__ __forceinline__ float sigmf(float x) { return 1.0f / (1.0f + expf(-x)); }

// ---------------- prep: lengths + stable descending rank + sync-state reset ----------------
__global__ __launch_bounds__(256) void prep_kernel(const int* __restrict__ x, int* __restrict__ len,
                                                   int* __restrict__ rank, int* __restrict__ arr) {
  __shared__ int sl[Bn];
  int t = threadIdx.x;
  if (t < 4) arr[t] = 0;          // per-cell counters cleared each call (deterministic)
  if (t < Bn) {
    int cnt = 0;
    const int* row = x + (size_t)t * Tn;
    for (int i = 0; i < Tn; ++i) cnt += (row[i] > 0) ? 1 : 0;
    sl[t] = cnt;
  }
  __syncthreads();
  if (t < Bn) {
    int Lb = sl[t], r = 0;
    for (int j = 0; j < Bn; ++j) {
      int lj = sl[j];
      r += ((lj > Lb) || (lj == Lb && j < t)) ? 1 : 0;
    }
    len[t] = Lb;
    rank[t] = r;
  }
}

// ---------------- bias fold ----------------
__global__ void bias_kernel(const float* __restrict__ bih, const float* __restrict__ bhh,
                            float* __restrict__ bias) {
  int i = blockIdx.x * blockDim.x + threadIdx.x;
  if (i < Ln * GN) bias[i] = bih[i] + bhh[i];
}

// ---------------- cast + permute weights into W_cat block layout ----------------
// Wlay[l][n][k]: n = bn*64 + j, j = strip*16 + hcl
// gate row g = strip*1024 + bn*16 + hcl ; k<1024 -> Wih[g][k], k>=1024 -> Whh[g][k-1024]
__global__ __launch_bounds__(256) void cast_w_kernel(const float* __restrict__ Wih,
                                                     const float* __restrict__ Whh,
                                                     unsigned short* __restrict__ Wlay) {
  size_t i = (size_t)blockIdx.x * blockDim.x + threadIdx.x; // (l, n, k4)
  int k4 = (int)(i & 511);
  int n  = (int)((i >> 9) & 4095);
  int l  = (int)(i >> 21);
  int bn = n >> 6, j = n & 63;
  int strip = j >> 4, hcl = j & 15;
  int g = strip * 1024 + bn * 16 + hcl;
  int k = k4 * 4;
  f32x4 v;
  if (k < 1024) v = *(const f32x4*)(Wih + ((size_t)l * GN + g) * Hn + k);
  else          v = *(const f32x4*)(Whh + ((size_t)l * GN + g) * Hn + (k - 1024));
  u16x4 pv;
#pragma unroll
  for (int u = 0; u < 4; ++u) pv[u] = f2bf(v[u]);
  *(u16x4*)(Wlay + i * 4) = pv;
}

// ---------------- embedding gather ----------------
__global__ __launch_bounds__(256) void embed_kernel(const int* __restrict__ x,
                                                    const float* __restrict__ emb,
                                                    unsigned short* __restrict__ Xemb) {
  int row = blockIdx.x;        // t*64 + b
  int t = row >> 6, b = row & 63;
  int tok = x[(size_t)b * Tn + t];
  f32x4 v = ((const f32x4*)(emb + (size_t)tok * Hn))[threadIdx.x];
  u16x4 p;
#pragma unroll
  for (int u = 0; u < 4; ++u) p[u] = f2bf(v[u]);
  ((u16x4*)(Xemb + (size_t)row * Hn))[threadIdx.x] = p;
}

// ---------------- init hmask: all 4 depth buffers ----------------
__global__ __launch_bounds__(256) void init_hmask_kernel(const float* __restrict__ h0,
                                                         unsigned short* __restrict__ hmask) {
  int i = blockIdx.x * blockDim.x + threadIdx.x;   // LBH
  unsigned short us = f2bf(h0[i]);
#pragma unroll
  for (int dep = 0; dep < 4; ++dep)
    hmask[(size_t)dep * LBH + i] = us;
}

// stage phase ph: in-chunk -> buf[0,16K), hm-chunk -> buf[16K,32K). 4 loads/thread.
__device__ __forceinline__ void stage2(const char* inb, const char* hmb, int ph, char* buf,
                                       int tid, bool cohIn) {
#pragma unroll
  for (int j = 0; j < 2; ++j) {
    int o = j * 8192 + tid * 16;
    int row = o >> 8, win = o & 255;
    int sw = win ^ ((row & 15) << 4);
    const char* s1 = inb + (size_t)row * 2048 + ph * 256 + sw;
    if (cohIn) gload16c(s1, buf + o);
    else       gload16(s1, buf + o);
    gload16c(hmb + (size_t)row * 2048 + ph * 256 + sw, buf + 16384 + o);
  }
}

// ---------------- persistent wavefront: W in regs, K-split waves, per-cell sync ----------------
// grid 256 blocks x 512 threads; cell = (bid&7)>>1, bn = (bid&1)*32 + (bid>>3)
// wave w: kq = w>>1 (K quarter: kq<2 -> x-part, kq>=2 -> h-part), sp = w&1 (strips sp*2, sp*2+1)
__global__ __launch_bounds__(512, 2) void wavefront_kernel(
    const char* __restrict__ Wlay, const float* __restrict__ biasF,
    const char* __restrict__ Xemb,
    unsigned short* __restrict__ hmask, unsigned short* __restrict__ hfresh,
    const int* __restrict__ len, const int* __restrict__ rankp,
    const float* __restrict__ h0, const float* __restrict__ c0,
    float* __restrict__ outp, float* __restrict__ hF, float* __restrict__ cF,
    int* __restrict__ arr) {
  __shared__ char smem[98304];   // 3 staging bufs x 32KB; exchange reuses buf0+buf2
  int tid = threadIdx.x, bid = blockIdx.x;
  int cell = (bid & 7) >> 1;
  int bn = (bid & 1) * 32 + (bid >> 3);
  int w = tid >> 6, lane = tid & 63, l15 = lane & 15, lk = lane >> 4;
  int kq = w >> 1, sp = w & 1;

  // one-time W preload: 32 bf16x8 = 128 regs (2 strips x 8 phases x 2 K-steps)
  bf16x8 wreg[32];
#pragma unroll
  for (int st = 0; st < 2; ++st) {
    const char* wr = Wlay + ((size_t)((cell * 64 + bn) * 64 + (sp * 2 + st) * 16 + l15)) * 4096
                   + (kq >= 2 ? 2048 : 0) + (kq & 1) * 128 + lk * 16;
#pragma unroll
    for (int ph = 0; ph < 8; ++ph)
#pragma unroll
      for (int j = 0; j < 2; ++j)
        wreg[st * 16 + ph * 2 + j] = *(const bf16x8*)(wr + ph * 256 + j * 64);
  }

  // per-thread epilogue state (threads 0-255)
  int r = tid >> 2;
  int c0i = (tid & 3) << 2;
  int hc = bn * 16 + c0i;
  f32x4 bI = {}, bF = {}, bG = {}, bO = {}, hold = {}, cold = {};
  int lenr = 0, rnkr = 0;
  if (tid < 256) {
    const float* bias = biasF + cell * GN;
    bI = *(const f32x4*)(bias + hc);
    bF = *(const f32x4*)(bias + 1024 + hc);
    bG = *(const f32x4*)(bias + 2048 + hc);
    bO = *(const f32x4*)(bias + 3072 + hc);
    lenr = len[r];
    rnkr = rankp[r];
    hold = *(const f32x4*)(h0 + ((size_t)cell * Bn + r) * Hn + hc);
    cold = *(const f32x4*)(c0 + ((size_t)cell * Bn + r) * Hn + hc);
  }

  for (int d = 0; d < NDIAG; ++d) {
    int t = d - cell;
    if (t >= 0 && t < Tn) {
      // ---- per-cell dependency polls (LLC counters, monotonic) ----
      if (tid == 0 && cell > 0) {
        int thr = 64 * d;
        while (__hip_atomic_load(&arr[cell - 1], __ATOMIC_RELAXED, __HIP_MEMORY_SCOPE_AGENT) < thr)
          __builtin_amdgcn_s_sleep(1);
      }
      if (tid == 1) {
        int thr = 64 * d;
        while (__hip_atomic_load(&arr[cell], __ATOMIC_RELAXED, __HIP_MEMORY_SCOPE_AGENT) < thr)
          __builtin_amdgcn_s_sleep(1);
      }
      if (tid == 2 && cell < Ln - 1 && d >= 2) {
        int thr = 64 * (d - 2);
        while (__hip_atomic_load(&arr[cell + 1], __ATOMIC_RELAXED, __HIP_MEMORY_SCOPE_AGENT) < thr)
          __builtin_amdgcn_s_sleep(1);
      }
      __syncthreads();

      bool cohIn = (cell != 0);
      const char* inbase = (cell == 0)
          ? (Xemb + (size_t)t * (Bn * Hn * 2))
          : (const char*)(hfresh + ((size_t)((d - 1) & 3) * Ln + (cell - 1)) * (Bn * Hn));
      const char* hmbase = (const char*)(hmask + ((size_t)((d - 1) & 3) * Ln + cell) * (Bn * Hn));
      unsigned short* hmW = hmask + ((size_t)(d & 3) * Ln + cell) * (Bn * Hn);
      unsigned short* hfW = hfresh + ((size_t)(d & 3) * Ln + cell) * (Bn * Hn);

      f32x4 acc[2][4] = {};
      stage2(inbase, hmbase, 0, smem, tid, cohIn);
      stage2(inbase, hmbase, 1, smem + 32768, tid, cohIn);
#pragma unroll
      for (int ph = 0; ph < 8; ++ph) {
        if (ph < 7) asm volatile("s_waitcnt vmcnt(4)" ::: "memory");
        else        asm volatile("s_waitcnt vmcnt(0)" ::: "memory");
        __builtin_amdgcn_s_barrier();
        if (ph < 6) stage2(inbase, hmbase, ph + 2, smem + ((ph + 2) % 3) * 32768, tid, cohIn);
        const char* chunk = smem + (ph % 3) * 32768 + (kq >= 2 ? 16384 : 0);
        int colb = (kq & 1) * 128;
#pragma unroll
        for (int j = 0; j < 2; ++j) {
#pragma unroll
          for (int mi = 0; mi < 4; ++mi) {
            int row = mi * 16 + l15;
            bf16x8 afr = *(const bf16x8*)(chunk + row * 256 +
                          ((colb + j * 64 + lk * 16) ^ ((row & 15) << 4)));
            acc[0][mi] = __builtin_amdgcn_mfma_f32_16x16x32_bf16(afr, wreg[ph * 2 + j],
                                                                 acc[0][mi], 0, 0, 0);
            acc[1][mi] = __builtin_amdgcn_mfma_f32_16x16x32_bf16(afr, wreg[16 + ph * 2 + j],
                                                                 acc[1][mi], 0, 0, 0);
          }
        }
      }

      // exchange: region ri = kq*4 + strip (4KB each); ri<8 -> buf0, ri>=8 -> buf2 (buf1 in use)
#pragma unroll
      for (int st = 0; st < 2; ++st) {
        int ri = kq * 4 + (sp * 2 + st);
        float* exf = (float*)(smem + (ri < 8 ? ri * 4096 : 32768 + ri * 4096));
#pragma unroll
        for (int mi = 0; mi < 4; ++mi)
#pragma unroll
          for (int j = 0; j < 4; ++j)
            exf[(mi * 16 + lk * 4 + j) * 16 + l15] = acc[st][mi][j];
      }
      __syncthreads();

      if (tid < 256) {
        f32x4 sv[4];
#pragma unroll
        for (int g = 0; g < 4; ++g) {
          f32x4 s = {};
#pragma unroll
          for (int q = 0; q < 4; ++q) {
            int ri = q * 4 + g;
            const float* exf = (const float*)(smem + (ri < 8 ? ri * 4096 : 32768 + ri * 4096));
            f32x4 v = *(const f32x4*)(exf + r * 16 + c0i);
#pragma unroll
            for (int u = 0; u < 4; ++u) s[u] += v[u];
          }
          sv[g] = s;
        }
        bool msk = (t < lenr);
        f32x4 hx;
#pragma unroll
        for (int u = 0; u < 4; ++u) {
          float iv = sigmf(sv[0][u] + bI[u]);
          float fv = sigmf(sv[1][u] + bF[u]);
          float gv = tanhf(sv[2][u] + bG[u]);
          float ov = sigmf(sv[3][u] + bO[u]);
          float cc = fv * cold[u] + iv * gv;
          float hh = ov * tanhf(cc);
          hx[u] = hh;
          cold[u] = msk ? cc : cold[u];
          hold[u] = msk ? hh : hold[u];
        }
        unsigned hb01 = (unsigned)f2bf(hold[0]) | ((unsigned)f2bf(hold[1]) << 16);
        unsigned hb23 = (unsigned)f2bf(hold[2]) | ((unsigned)f2bf(hold[3]) << 16);
        unsigned xb01 = (unsigned)f2bf(hx[0]) | ((unsigned)f2bf(hx[1]) << 16);
        unsigned xb23 = (unsigned)f2bf(hx[2]) | ((unsigned)f2bf(hx[3]) << 16);
        unsigned* hm32 = (unsigned*)(hmW + (size_t)r * Hn + hc);
        unsigned* hf32p = (unsigned*)(hfW + (size_t)r * Hn + hc);
        __hip_atomic_store(hm32,     hb01, __ATOMIC_RELAXED, __HIP_MEMORY_SCOPE_AGENT);
        __hip_atomic_store(hm32 + 1, hb23, __ATOMIC_RELAXED, __HIP_MEMORY_SCOPE_AGENT);
        __hip_atomic_store(hf32p,     xb01, __ATOMIC_RELAXED, __HIP_MEMORY_SCOPE_AGENT);
        __hip_atomic_store(hf32p + 1, xb23, __ATOMIC_RELAXED, __HIP_MEMORY_SCOPE_AGENT);
        if (cell == Ln - 1) {
          f32x4 o4;
#pragma unroll
          for (int u = 0; u < 4; ++u) o4[u] = msk ? hx[u] : 0.0f;
          *(f32x4*)(outp + ((size_t)r * Tn + t) * Hn + hc) = o4;
        }
      }
    }

    // ---- completion signal: all waves' stores drained, then one increment ----
    __syncthreads();
    if (tid == 0)
      __hip_atomic_fetch_add(&arr[cell], 1, __ATOMIC_RELAXED, __HIP_MEMORY_SCOPE_AGENT);
  }

  // final state writeback with rank permutation (state lived in registers)
  if (tid < 256) {
    *(f32x4*)(hF + ((size_t)cell * Bn + rnkr) * Hn + hc) = hold;
    *(f32x4*)(cF + ((size_t)cell * Bn + rnkr) * Hn + hc) = cold;
  }
}

extern "C" void kernel_launch(void* const* d_in, const int* in_sizes, int n_in,
                              void* d_out, int out_size, void* d_ws, size_t ws_size,
                              hipStream_t stream) {
  const int*   x   = (const int*)d_in[0];
  const float* h0  = (const float*)d_in[1];
  const float* c0  = (const float*)d_in[2];
  const float* emb = (const float*)d_in[3];
  const float* Wih = (const float*)d_in[4];
  const float* Whh = (const float*)d_in[5];
  const float* bih = (const float*)d_in[6];
  const float* bhh = (const float*)d_in[7];
  float* out = (float*)d_out;

  char* ws = (char*)d_ws;
  unsigned short* Wlay  = (unsigned short*)ws;                   // 67108864 B
  float*          biasF = (float*)(ws + 67108864);               // 65536 B
  unsigned short* Xemb  = (unsigned short*)(ws + 67174400);      // 67108864 B
  unsigned short* hmask = (unsigned short*)(ws + 134283264);     // 2097152 B (4 depths)
  unsigned short* hfresh= (unsigned short*)(ws + 136380416);     // 2097152 B (4 depths)
  int*            leni  = (int*)(ws + 138477568);
  int*            ranki = (int*)(ws + 138477824);
  int*            arrp  = (int*)(ws + 138478080);                // 4 per-cell counters

  prep_kernel<<<1, 256, 0, stream>>>(x, leni, ranki, arrp);
  bias_kernel<<<64, 256, 0, stream>>>(bih, bhh, biasF);
  cast_w_kernel<<<32768, 256, 0, stream>>>(Wih, Whh, Wlay);
  embed_kernel<<<Tn * Bn, 256, 0, stream>>>(x, emb, Xemb);
  init_hmask_kernel<<<1024, 256, 0, stream>>>(h0, hmask);

  float* hFbase = out + (size_t)Bn * Tn * Hn;
  float* cFbase = hFbase + (size_t)Ln * Bn * Hn;

  wavefront_kernel<<<256, 512, 0, stream>>>(
      (const char*)Wlay, biasF, (const char*)Xemb, hmask, hfresh,
      leni, ranki, h0, c0, out, hFbase, cFbase, arrp);
}

// Round 8
// 5169.926 us; speedup vs baseline: 1.0889x; 1.0889x over previous
//
#include <hip/hip_runtime.h>
#include <hip/hip_bf16.h>
#include <stdint.h>

#define Bn 64
#define Tn 512
#define Hn 1024
#define Ln 4
#define GN 4096   // 4*H
#define NDIAG (Tn + Ln - 1)
#define LBH (Ln * Bn * Hn)

typedef __attribute__((ext_vector_type(8))) short bf16x8;
typedef __attribute__((ext_vector_type(4))) float f32x4;
typedef __attribute__((ext_vector_type(4))) unsigned short u16x4;

__device__ __forceinline__ unsigned short f2bf(float f) {
  union { float f; unsigned u; } v; v.f = f;
  return (unsigned short)((v.u + 0x7FFFu + ((v.u >> 16) & 1u)) >> 16);
}

// cached global->LDS 16B (L2-cacheable — panel broadcast path)
__device__ __forceinline__ void gload16(const void* g, void* l) {
  __builtin_amdgcn_global_load_lds((const __attribute__((address_space(1))) void*)g,
                                   (__attribute__((address_space(3))) void*)l, 16, 0, 0);
}

__device__ __forceinline__ float sigmf(float x) { return 1.0f / (1.0f + expf(-x)); }

// ---------------- prep: lengths + stable descending rank + sync-slot reset ----------------
__global__ __launch_bounds__(256) void prep_kernel(const int* __restrict__ x, int* __restrict__ len,
                                                   int* __restrict__ rank, int* __restrict__ arr) {
  __shared__ int sl[Bn];
  int t = threadIdx.x;
  arr[t] = 0;                     // 256 slots (4 cells x 64 blocks) cleared each call
  if (t < Bn) {
    int cnt = 0;
    const int* row = x + (size_t)t * Tn;
    for (int i = 0; i < Tn; ++i) cnt += (row[i] > 0) ? 1 : 0;
    sl[t] = cnt;
  }
  __syncthreads();
  if (t < Bn) {
    int Lb = sl[t], r = 0;
    for (int j = 0; j < Bn; ++j) {
      int lj = sl[j];
      r += ((lj > Lb) || (lj == Lb && j < t)) ? 1 : 0;
    }
    len[t] = Lb;
    rank[t] = r;
  }
}

// ---------------- bias fold ----------------
__global__ void bias_kernel(const float* __restrict__ bih, const float* __restrict__ bhh,
                            float* __restrict__ bias) {
  int i = blockIdx.x * blockDim.x + threadIdx.x;
  if (i < Ln * GN) bias[i] = bih[i] + bhh[i];
}

// ---------------- cast + permute weights into W_cat block layout ----------------
// Wlay[l][n][k]: n = bn*64 + j, j = strip*16 + hcl
// gate row g = strip*1024 + bn*16 + hcl ; k<1024 -> Wih[g][k], k>=1024 -> Whh[g][k-1024]
__global__ __launch_bounds__(256) void cast_w_kernel(const float* __restrict__ Wih,
                                                     const float* __restrict__ Whh,
                                                     unsigned short* __restrict__ Wlay) {
  size_t i = (size_t)blockIdx.x * blockDim.x + threadIdx.x; // (l, n, k4)
  int k4 = (int)(i & 511);
  int n  = (int)((i >> 9) & 4095);
  int l  = (int)(i >> 21);
  int bn = n >> 6, j = n & 63;
  int strip = j >> 4, hcl = j & 15;
  int g = strip * 1024 + bn * 16 + hcl;
  int k = k4 * 4;
  f32x4 v;
  if (k < 1024) v = *(const f32x4*)(Wih + ((size_t)l * GN + g) * Hn + k);
  else          v = *(const f32x4*)(Whh + ((size_t)l * GN + g) * Hn + (k - 1024));
  u16x4 pv;
#pragma unroll
  for (int u = 0; u < 4; ++u) pv[u] = f2bf(v[u]);
  *(u16x4*)(Wlay + i * 4) = pv;
}

// ---------------- embedding gather ----------------
__global__ __launch_bounds__(256) void embed_kernel(const int* __restrict__ x,
                                                    const float* __restrict__ emb,
                                                    unsigned short* __restrict__ Xemb) {
  int row = blockIdx.x;        // t*64 + b
  int t = row >> 6, b = row & 63;
  int tok = x[(size_t)b * Tn + t];
  f32x4 v = ((const f32x4*)(emb + (size_t)tok * Hn))[threadIdx.x];
  u16x4 p;
#pragma unroll
  for (int u = 0; u < 4; ++u) p[u] = f2bf(v[u]);
  ((u16x4*)(Xemb + (size_t)row * Hn))[threadIdx.x] = p;
}

// ---------------- init hmask: all 4 depth buffers ----------------
__global__ __launch_bounds__(256) void init_hmask_kernel(const float* __restrict__ h0,
                                                         unsigned short* __restrict__ hmask) {
  int i = blockIdx.x * blockDim.x + threadIdx.x;   // LBH
  unsigned short us = f2bf(h0[i]);
#pragma unroll
  for (int dep = 0; dep < 4; ++dep)
    hmask[(size_t)dep * LBH + i] = us;
}

// stage phase ph: in-chunk -> buf[0,16K), hm-chunk -> buf[16K,32K). 4 loads/thread.
__device__ __forceinline__ void stage2(const char* inb, const char* hmb, int ph, char* buf, int tid) {
#pragma unroll
  for (int j = 0; j < 2; ++j) {
    int o = j * 8192 + tid * 16;
    int row = o >> 8, win = o & 255;
    int sw = win ^ ((row & 15) << 4);
    gload16(inb + (size_t)row * 2048 + ph * 256 + sw, buf + o);
    gload16(hmb + (size_t)row * 2048 + ph * 256 + sw, buf + 16384 + o);
  }
}

// ---------------- persistent wavefront: W in regs, L2-cached panels + per-diag acquire inv ----------------
// grid 256 blocks x 512 threads; cell = (bid&7)>>1 (XCD-paired), bn = (bid&1)*32 + (bid>>3)
// wave w: kq = w>>1 (K quarter: kq<2 -> x-part, kq>=2 -> h-part), sp = w&1 (strips sp*2, sp*2+1)
__global__ __launch_bounds__(512, 2) void wavefront_kernel(
    const char* __restrict__ Wlay, const float* __restrict__ biasF,
    const char* __restrict__ Xemb,
    unsigned short* __restrict__ hmask, unsigned short* __restrict__ hfresh,
    const int* __restrict__ len, const int* __restrict__ rankp,
    const float* __restrict__ h0, const float* __restrict__ c0,
    float* __restrict__ outp, float* __restrict__ hF, float* __restrict__ cF,
    int* __restrict__ arr) {
  __shared__ char smem[98304];   // 3 staging bufs x 32KB; exchange reuses buf0+buf2
  int tid = threadIdx.x, bid = blockIdx.x;
  int cell = (bid & 7) >> 1;
  int bn = (bid & 1) * 32 + (bid >> 3);
  int w = tid >> 6, lane = tid & 63, l15 = lane & 15, lk = lane >> 4;
  int kq = w >> 1, sp = w & 1;

  // one-time W preload: 32 bf16x8 = 128 regs (2 strips x 8 phases x 2 K-steps)
  bf16x8 wreg[32];
#pragma unroll
  for (int st = 0; st < 2; ++st) {
    const char* wr = Wlay + ((size_t)((cell * 64 + bn) * 64 + (sp * 2 + st) * 16 + l15)) * 4096
                   + (kq >= 2 ? 2048 : 0) + (kq & 1) * 128 + lk * 16;
#pragma unroll
    for (int ph = 0; ph < 8; ++ph)
#pragma unroll
      for (int j = 0; j < 2; ++j)
        wreg[st * 16 + ph * 2 + j] = *(const bf16x8*)(wr + ph * 256 + j * 64);
  }

  // per-thread epilogue state (threads 0-255)
  int r = tid >> 2;
  int c0i = (tid & 3) << 2;
  int hc = bn * 16 + c0i;
  f32x4 bI = {}, bF = {}, bG = {}, bO = {}, hold = {}, cold = {};
  int lenr = 0, rnkr = 0;
  if (tid < 256) {
    const float* bias = biasF + cell * GN;
    bI = *(const f32x4*)(bias + hc);
    bF = *(const f32x4*)(bias + 1024 + hc);
    bG = *(const f32x4*)(bias + 2048 + hc);
    bO = *(const f32x4*)(bias + 3072 + hc);
    lenr = len[r];
    rnkr = rankp[r];
    hold = *(const f32x4*)(h0 + ((size_t)cell * Bn + r) * Hn + hc);
    cold = *(const f32x4*)(c0 + ((size_t)cell * Bn + r) * Hn + hc);
  }

  for (int d = 0; d < NDIAG; ++d) {
    int t = d - cell;
    if (t >= 0 && t < Tn) {
      // ---- wave-parallel dependency polls (lane = producer slot, __all ballot) ----
      if (w == 0 && cell > 0) {                 // prev cell completed diag d-1
        for (;;) {
          int v = __hip_atomic_load(&arr[(cell - 1) * 64 + lane], __ATOMIC_RELAXED,
                                    __HIP_MEMORY_SCOPE_AGENT);
          if (__all(v >= d)) break;
          __builtin_amdgcn_s_sleep(1);
        }
      }
      if (w == 1) {                             // own cell completed diag d-1
        for (;;) {
          int v = __hip_atomic_load(&arr[cell * 64 + lane], __ATOMIC_RELAXED,
                                    __HIP_MEMORY_SCOPE_AGENT);
          if (__all(v >= d)) break;
          __builtin_amdgcn_s_sleep(1);
        }
      }
      if (w == 2 && cell < Ln - 1 && d >= 2) {  // next cell completed diag d-3 (overwrite safety)
        for (;;) {
          int v = __hip_atomic_load(&arr[(cell + 1) * 64 + lane], __ATOMIC_RELAXED,
                                    __HIP_MEMORY_SCOPE_AGENT);
          if (__all(v >= d - 2)) break;
          __builtin_amdgcn_s_sleep(1);
        }
      }
      __syncthreads();
      // one acquire fence per block: invalidate L1 + XCD-L2 so cached panel reads see LLC truth
      if (tid == 0) __builtin_amdgcn_fence(__ATOMIC_ACQUIRE, "agent");
      __syncthreads();

      const char* inbase = (cell == 0)
          ? (Xemb + (size_t)t * (Bn * Hn * 2))
          : (const char*)(hfresh + ((size_t)((d - 1) & 3) * Ln + (cell - 1)) * (Bn * Hn));
      const char* hmbase = (const char*)(hmask + ((size_t)((d - 1) & 3) * Ln + cell) * (Bn * Hn));
      unsigned short* hmW = hmask + ((size_t)(d & 3) * Ln + cell) * (Bn * Hn);
      unsigned short* hfW = hfresh + ((size_t)(d & 3) * Ln + cell) * (Bn * Hn);

      f32x4 acc[2][4] = {};
      stage2(inbase, hmbase, 0, smem, tid);
      stage2(inbase, hmbase, 1, smem + 32768, tid);
#pragma unroll
      for (int ph = 0; ph < 8; ++ph) {
        if (ph < 7) asm volatile("s_waitcnt vmcnt(4)" ::: "memory");
        else        asm volatile("s_waitcnt vmcnt(0)" ::: "memory");
        __builtin_amdgcn_s_barrier();
        if (ph < 6) stage2(inbase, hmbase, ph + 2, smem + ((ph + 2) % 3) * 32768, tid);
        const char* chunk = smem + (ph % 3) * 32768 + (kq >= 2 ? 16384 : 0);
        int colb = (kq & 1) * 128;
#pragma unroll
        for (int j = 0; j < 2; ++j) {
#pragma unroll
          for (int mi = 0; mi < 4; ++mi) {
            int row = mi * 16 + l15;
            bf16x8 afr = *(const bf16x8*)(chunk + row * 256 +
                          ((colb + j * 64 + lk * 16) ^ ((row & 15) << 4)));
            acc[0][mi] = __builtin_amdgcn_mfma_f32_16x16x32_bf16(afr, wreg[ph * 2 + j],
                                                                 acc[0][mi], 0, 0, 0);
            acc[1][mi] = __builtin_amdgcn_mfma_f32_16x16x32_bf16(afr, wreg[16 + ph * 2 + j],
                                                                 acc[1][mi], 0, 0, 0);
          }
        }
      }

      // exchange: region ri = kq*4 + strip (4KB each); ri<8 -> buf0, ri>=8 -> buf2
#pragma unroll
      for (int st = 0; st < 2; ++st) {
        int ri = kq * 4 + (sp * 2 + st);
        float* exf = (float*)(smem + (ri < 8 ? ri * 4096 : 32768 + ri * 4096));
#pragma unroll
        for (int mi = 0; mi < 4; ++mi)
#pragma unroll
          for (int j = 0; j < 4; ++j)
            exf[(mi * 16 + lk * 4 + j) * 16 + l15] = acc[st][mi][j];
      }
      __syncthreads();

      if (tid < 256) {
        f32x4 sv[4];
#pragma unroll
        for (int g = 0; g < 4; ++g) {
          f32x4 s = {};
#pragma unroll
          for (int q = 0; q < 4; ++q) {
            int ri = q * 4 + g;
            const float* exf = (const float*)(smem + (ri < 8 ? ri * 4096 : 32768 + ri * 4096));
            f32x4 v = *(const f32x4*)(exf + r * 16 + c0i);
#pragma unroll
            for (int u = 0; u < 4; ++u) s[u] += v[u];
          }
          sv[g] = s;
        }
        bool msk = (t < lenr);
        f32x4 hx;
#pragma unroll
        for (int u = 0; u < 4; ++u) {
          float iv = sigmf(sv[0][u] + bI[u]);
          float fv = sigmf(sv[1][u] + bF[u]);
          float gv = tanhf(sv[2][u] + bG[u]);
          float ov = sigmf(sv[3][u] + bO[u]);
          float cc = fv * cold[u] + iv * gv;
          float hh = ov * tanhf(cc);
          hx[u] = hh;
          cold[u] = msk ? cc : cold[u];
          hold[u] = msk ? hh : hold[u];
        }
        unsigned hb01 = (unsigned)f2bf(hold[0]) | ((unsigned)f2bf(hold[1]) << 16);
        unsigned hb23 = (unsigned)f2bf(hold[2]) | ((unsigned)f2bf(hold[3]) << 16);
        unsigned xb01 = (unsigned)f2bf(hx[0]) | ((unsigned)f2bf(hx[1]) << 16);
        unsigned xb23 = (unsigned)f2bf(hx[2]) | ((unsigned)f2bf(hx[3]) << 16);
        unsigned* hm32 = (unsigned*)(hmW + (size_t)r * Hn + hc);
        unsigned* hf32p = (unsigned*)(hfW + (size_t)r * Hn + hc);
        __hip_atomic_store(hm32,     hb01, __ATOMIC_RELAXED, __HIP_MEMORY_SCOPE_AGENT);
        __hip_atomic_store(hm32 + 1, hb23, __ATOMIC_RELAXED, __HIP_MEMORY_SCOPE_AGENT);
        __hip_atomic_store(hf32p,     xb01, __ATOMIC_RELAXED, __HIP_MEMORY_SCOPE_AGENT);
        __hip_atomic_store(hf32p + 1, xb23, __ATOMIC_RELAXED, __HIP_MEMORY_SCOPE_AGENT);
        if (cell == Ln - 1) {
          f32x4 o4;
#pragma unroll
          for (int u = 0; u < 4; ++u) o4[u] = msk ? hx[u] : 0.0f;
          *(f32x4*)(outp + ((size_t)r * Tn + t) * Hn + hc) = o4;
        }
      }
    }

    // ---- arrival: all waves' stores drained by barrier, then one parallel slot store ----
    __syncthreads();
    if (tid == 0)
      __hip_atomic_store(&arr[cell * 64 + bn], d + 1, __ATOMIC_RELAXED, __HIP_MEMORY_SCOPE_AGENT);
  }

  // final state writeback with rank permutation (state lived in registers)
  if (tid < 256) {
    *(f32x4*)(hF + ((size_t)cell * Bn + rnkr) * Hn + hc) = hold;
    *(f32x4*)(cF + ((size_t)cell * Bn + rnkr) * Hn + hc) = cold;
  }
}

extern "C" void kernel_launch(void* const* d_in, const int* in_sizes, int n_in,
                              void* d_out, int out_size, void* d_ws, size_t ws_size,
                              hipStream_t stream) {
  const int*   x   = (const int*)d_in[0];
  const float* h0  = (const float*)d_in[1];
  const float* c0  = (const float*)d_in[2];
  const float* emb = (const float*)d_in[3];
  const float* Wih = (const float*)d_in[4];
  const float* Whh = (const float*)d_in[5];
  const float* bih = (const float*)d_in[6];
  const float* bhh = (const float*)d_in[7];
  float* out = (float*)d_out;

  char* ws = (char*)d_ws;
  unsigned short* Wlay  = (unsigned short*)ws;                   // 67108864 B
  float*          biasF = (float*)(ws + 67108864);               // 65536 B
  unsigned short* Xemb  = (unsigned short*)(ws + 67174400);      // 67108864 B
  unsigned short* hmask = (unsigned short*)(ws + 134283264);     // 2097152 B (4 depths)
  unsigned short* hfresh= (unsigned short*)(ws + 136380416);     // 2097152 B (4 depths)
  int*            leni  = (int*)(ws + 138477568);
  int*            ranki = (int*)(ws + 138477824);
  int*            arrp  = (int*)(ws + 138478080);                // 256 arrival slots (4x64)

  prep_kernel<<<1, 256, 0, stream>>>(x, leni, ranki, arrp);
  bias_kernel<<<64, 256, 0, stream>>>(bih, bhh, biasF);
  cast_w_kernel<<<32768, 256, 0, stream>>>(Wih, Whh, Wlay);
  embed_kernel<<<Tn * Bn, 256, 0, stream>>>(x, emb, Xemb);
  init_hmask_kernel<<<1024, 256, 0, stream>>>(h0, hmask);

  float* hFbase = out + (size_t)Bn * Tn * Hn;
  float* cFbase = hFbase + (size_t)Ln * Bn * Hn;

  wavefront_kernel<<<256, 512, 0, stream>>>(
      (const char*)Wlay, biasF, (const char*)Xemb, hmask, hfresh,
      leni, ranki, h0, c0, out, hFbase, cFbase, arrp);
}